// Round 5
// baseline (198.224 us; speedup 1.0000x reference)
//
#include <hip/hip_runtime.h>

#define BATCH 1024
#define SEQ   200
#define EMB   128
#define VOCAB 100000

typedef __attribute__((ext_vector_type(8))) short short8;
typedef __attribute__((ext_vector_type(4))) float f32x4;

__device__ __forceinline__ unsigned short f2bf(float x) {
  unsigned u = __float_as_uint(x);
  u += 0x7fffu + ((u >> 16) & 1u);   // RNE
  return (unsigned short)(u >> 16);
}
__device__ __forceinline__ float bf2f(unsigned short b) {
  return __uint_as_float(((unsigned)b) << 16);
}

// ---------------------------------------------------------------------------
// One-time: emb table fp32 -> bf16 (RNE).
// ---------------------------------------------------------------------------
__global__ __launch_bounds__(256) void cvt_emb(const float* __restrict__ src,
                                               unsigned short* __restrict__ dst) {
  size_t i = ((size_t)blockIdx.x * 256 + threadIdx.x) * 8;
  float4 a = *(const float4*)(src + i);
  float4 b = *(const float4*)(src + i + 4);
  short8 o;
  o[0]=(short)f2bf(a.x); o[1]=(short)f2bf(a.y); o[2]=(short)f2bf(a.z); o[3]=(short)f2bf(a.w);
  o[4]=(short)f2bf(b.x); o[5]=(short)f2bf(b.y); o[6]=(short)f2bf(b.z); o[7]=(short)f2bf(b.w);
  *(short8*)(dst + i) = o;
}

// ---------------------------------------------------------------------------
// rnn5: 256 blocks x 512 thr (8 waves, 2/SIMD). Block owns 4 batch rows.
// Plain bf16 recurrence (error model: ~5e-4 total, verified r1 vs r3/r4
// absmax identical => recurrence precision dominated by emb-bf16 anyway).
// Per wave per step: 4 ds_read_b128 (h) + 8 MFMA (4 Wh·h + 4 Win·e, the
// latter pipelined one step ahead with bias in C-init) + 4 global dwordx4
// (emb rows, 2 steps ahead, compiler-counted vmcnt) + tanh/pack for 4
// outputs + 1 b64 h-write + raw lgkmcnt(0)+s_barrier (vmcnt never drained).
// h tile [4 r][128 f] bf16, chunk-XOR swizzle (^(r<<2) on chunk idx).
// ---------------------------------------------------------------------------
__global__ __launch_bounds__(512, 2) void rnn5(
    const int* __restrict__ xidx, const unsigned short* __restrict__ embb,
    const float* __restrict__ Win, const float* __restrict__ bin,
    const float* __restrict__ Wh,  const float* __restrict__ bh,
    float* __restrict__ out)
{
  __shared__ unsigned short hbuf[2][4][EMB];   // 2KB double-buffered h
  __shared__ int   xl[4][SEQ];                 // 3.2KB indices
  __shared__ float red[4][8];

  const int tid = threadIdx.x;
  const int w   = tid >> 6;          // f-tile
  const int l   = tid & 63;
  const int l15 = l & 15;
  const int lhi = l >> 4;            // 0..3
  const int r   = l15 & 3;           // batch row (cols 4..15 duplicate)
  const int r0  = blockIdx.x * 4;

  // A-fragments: A[row=l15][k=kc*32+lhi*8+j] = W[w*16+l15][k], bf16 RNE
  short8 wi[4], whh[4];
  f32x4  biasv;
  {
    const int frow = w*16 + l15;
    const float* pw = Win + frow*EMB;
    const float* ph = Wh  + frow*EMB;
#pragma unroll
    for (int kc = 0; kc < 4; ++kc) {
      float4 a = ((const float4*)(pw + kc*32 + lhi*8))[0];
      float4 b = ((const float4*)(pw + kc*32 + lhi*8))[1];
      float vw[8] = {a.x,a.y,a.z,a.w,b.x,b.y,b.z,b.w};
      float4 c = ((const float4*)(ph + kc*32 + lhi*8))[0];
      float4 d = ((const float4*)(ph + kc*32 + lhi*8))[1];
      float vh[8] = {c.x,c.y,c.z,c.w,d.x,d.y,d.z,d.w};
      short8 fw, fh;
#pragma unroll
      for (int j = 0; j < 8; ++j) { fw[j] = (short)f2bf(vw[j]); fh[j] = (short)f2bf(vh[j]); }
      wi[kc] = fw; whh[kc] = fh;
    }
    const int fo = w*16 + lhi*4;
    biasv[0] = bin[fo+0] + bh[fo+0];
    biasv[1] = bin[fo+1] + bh[fo+1];
    biasv[2] = bin[fo+2] + bh[fo+2];
    biasv[3] = bin[fo+3] + bh[fo+3];
  }

  // stage x indices; zero h buffer 0 (1KB = 256 uints)
  for (int i = tid; i < 4*SEQ; i += 512)
    xl[i / SEQ][i % SEQ] = xidx[(r0 + i/SEQ)*SEQ + (i % SEQ)];
  char* hb = (char*)&hbuf[0][0][0];
  if (tid < 256) ((unsigned int*)hb)[tid] = 0u;
  __syncthreads();

  // precomputed swizzled LDS offsets.
  // read:  chunk(kc) = (kc*4+lhi) ^ (r<<2)  -> offh[kc]
  // write: chunk      = (2w + (lhi>>1)) ^ (r<<2), +8B if lhi odd
  int offh[4];
#pragma unroll
  for (int kc = 0; kc < 4; ++kc)
    offh[kc] = r*256 + (((kc*4 + lhi) ^ (r << 2)) << 4);
  const int offw = r*256 + (((2*w + (lhi >> 1)) ^ (r << 2)) << 4) + (lhi & 1)*8;

  // emb row fetch: lane reads 16B at (xi*128 + lhi*8 + kc*32) elems
  const unsigned short* ebase = embb + lhi*8;

  // prologue: ef(0) -> ae_cur; ef(1) -> ef_pre; xi pipeline for s+2
  f32x4 ae_cur = biasv;
  short8 ef_pre[4];
  {
    const unsigned short* p0 = ebase + (size_t)xl[r][0]*EMB;
    const unsigned short* p1 = ebase + (size_t)xl[r][1]*EMB;
    short8 e0[4];
#pragma unroll
    for (int kc = 0; kc < 4; ++kc) { e0[kc] = *(const short8*)(p0 + kc*32); }
#pragma unroll
    for (int kc = 0; kc < 4; ++kc) { ef_pre[kc] = *(const short8*)(p1 + kc*32); }
#pragma unroll
    for (int kc = 0; kc < 4; ++kc)
      ae_cur = __builtin_amdgcn_mfma_f32_16x16x32_bf16(wi[kc], e0[kc], ae_cur, 0, 0, 0);
  }
  int xi_cur = xl[r][2 < SEQ ? 2 : SEQ-1];

  float hfin[4];
  for (int s = 0; s < SEQ; ++s) {
    // issue emb loads for step s+2 (in-flight across barriers; compiler
    // inserts counted vmcnt before first use next iteration)
    short8 efn[4];
    {
      const unsigned short* ep = ebase + (size_t)xi_cur*EMB;
#pragma unroll
      for (int kc = 0; kc < 4; ++kc) efn[kc] = *(const short8*)(ep + kc*32);
    }
    const int sn = (s + 3 < SEQ) ? s + 3 : SEQ - 1;
    const int xi_n = xl[r][sn];

    // h reads + Wh·h chain
    const char* th = hb + (s & 1)*1024;
    f32x4 a0 = (f32x4)(0.0f);
    short8 hh[4];
#pragma unroll
    for (int kc = 0; kc < 4; ++kc) hh[kc] = *(const short8*)(th + offh[kc]);
#pragma unroll
    for (int kc = 0; kc < 4; ++kc)
      a0 = __builtin_amdgcn_mfma_f32_16x16x32_bf16(whh[kc], hh[kc], a0, 0, 0, 0);

    // Win·e for NEXT step (independent of h; bias in C-init)
    f32x4 aen = biasv;
#pragma unroll
    for (int kc = 0; kc < 4; ++kc)
      aen = __builtin_amdgcn_mfma_f32_16x16x32_bf16(wi[kc], ef_pre[kc], aen, 0, 0, 0);

    // finalize 4 outputs: v -> tanh -> RNE-bf16 pack -> b64 write
    unsigned int u[4];
#pragma unroll
    for (int j = 0; j < 4; ++j) {
      float v  = ae_cur[j] + a0[j];
      float e2 = __expf(2.0f * v);
      float hn = 1.0f - __fdividef(2.0f, e2 + 1.0f);
      hfin[j] = hn;
      u[j] = __float_as_uint(hn) + 0x8000u;   // round-half-up bf16
    }
    if (l15 < 4) {
      char* nh = hb + (((s + 1) & 1))*1024;
      uint2 pk;
      pk.x = (u[1] & 0xffff0000u) | (u[0] >> 16);
      pk.y = (u[3] & 0xffff0000u) | (u[2] >> 16);
      *(uint2*)(nh + offw) = pk;
    }

#pragma unroll
    for (int kc = 0; kc < 4; ++kc) ef_pre[kc] = efn[kc];
    ae_cur = aen;
    xi_cur = xi_n;

    // h-writes visible; emb loads for s+1/s+2 stay in flight (no vmcnt!)
    asm volatile("s_waitcnt lgkmcnt(0)\n\ts_barrier" ::: "memory");
  }

  // L2 normalize. Lane holds h[r][f = w*16+lhi*4+j].
  float pj = hfin[0]*hfin[0] + hfin[1]*hfin[1] + hfin[2]*hfin[2] + hfin[3]*hfin[3];
  pj += __shfl_xor(pj, 16, 64);
  pj += __shfl_xor(pj, 32, 64);          // summed over lhi -> wave partial
  if (l < 4) red[l][w] = pj;
  asm volatile("s_waitcnt lgkmcnt(0)\n\ts_barrier" ::: "memory");
  float tot = 0.0f;
#pragma unroll
  for (int g = 0; g < 8; ++g) tot += red[r][g];
  const float inv = 1.0f / fmaxf(sqrtf(tot), 1e-12f);
  if (l15 < 4) {
    float4 o;
    o.x = hfin[0]*inv; o.y = hfin[1]*inv; o.z = hfin[2]*inv; o.w = hfin[3]*inv;
    *(float4*)(out + (size_t)(r0 + r)*EMB + w*16 + lhi*4) = o;
  }
}

// ---------------------------------------------------------------------------
// Fallback (small ws): round-1 VALU recurrence (known-correct, no scratch).
// ---------------------------------------------------------------------------
__global__ __launch_bounds__(512) void rnn_fused(
    const int* __restrict__ xidx, const float* __restrict__ emb,
    const float* __restrict__ Win, const float* __restrict__ bin,
    const float* __restrict__ Wh,  const float* __restrict__ bh,
    float* __restrict__ out)
{
  __shared__ float h_lds[4][EMB];
  __shared__ float part[8][4][EMB];
  __shared__ float emb_lds[2][4][EMB];
  __shared__ int   x_lds[4][SEQ];
  __shared__ float red[8];

  const int t   = threadIdx.x;
  const int f0  = (t & 63) * 2;
  const int eg  = t >> 6;
  const int e0  = eg * 16;
  const int b0  = blockIdx.x * 4;
  const int row = t >> 7;
  const int ff  = t & 127;

  float wh0[16], wh1[16], wi0[16], wi1[16];
  {
    const float* p0 = Wh + f0*EMB + e0;
    const float* p1 = Wh + (f0+1)*EMB + e0;
    const float* q0 = Win + f0*EMB + e0;
    const float* q1 = Win + (f0+1)*EMB + e0;
#pragma unroll
    for (int q = 0; q < 4; ++q) {
      float4 a = ((const float4*)p0)[q];
      wh0[4*q+0]=a.x; wh0[4*q+1]=a.y; wh0[4*q+2]=a.z; wh0[4*q+3]=a.w;
      float4 b = ((const float4*)p1)[q];
      wh1[4*q+0]=b.x; wh1[4*q+1]=b.y; wh1[4*q+2]=b.z; wh1[4*q+3]=b.w;
      float4 c = ((const float4*)q0)[q];
      wi0[4*q+0]=c.x; wi0[4*q+1]=c.y; wi0[4*q+2]=c.z; wi0[4*q+3]=c.w;
      float4 d = ((const float4*)q1)[q];
      wi1[4*q+0]=d.x; wi1[4*q+1]=d.y; wi1[4*q+2]=d.z; wi1[4*q+3]=d.w;
    }
  }
  const float bc = bin[ff] + bh[ff];
  h_lds[row][ff] = 0.0f;
  for (int i = t; i < 4*SEQ; i += 512)
    x_lds[i / SEQ][i % SEQ] = xidx[(b0 + i/SEQ)*SEQ + (i % SEQ)];
  __syncthreads();
  emb_lds[0][row][ff] = emb[(long)x_lds[row][0]*EMB + ff];
  __syncthreads();

  int cur = 0;
  for (int s = 0; s < SEQ; ++s) {
    float nxt = 0.0f;
    if (s + 1 < SEQ) nxt = emb[(long)x_lds[row][s+1]*EMB + ff];
    float pa0[4], pa1[4];
#pragma unroll
    for (int rq = 0; rq < 4; ++rq) { pa0[rq] = 0.0f; pa1[rq] = 0.0f; }
#pragma unroll
    for (int rq = 0; rq < 4; ++rq) {
      const float4* hp  = (const float4*)&h_lds[rq][e0];
      const float4* epv = (const float4*)&emb_lds[cur][rq][e0];
#pragma unroll
      for (int q = 0; q < 4; ++q) {
        float4 hv = hp[q], ev = epv[q];
        pa0[rq] = fmaf(hv.x, wh0[4*q+0], pa0[rq]); pa0[rq] = fmaf(hv.y, wh0[4*q+1], pa0[rq]);
        pa0[rq] = fmaf(hv.z, wh0[4*q+2], pa0[rq]); pa0[rq] = fmaf(hv.w, wh0[4*q+3], pa0[rq]);
        pa1[rq] = fmaf(hv.x, wh1[4*q+0], pa1[rq]); pa1[rq] = fmaf(hv.y, wh1[4*q+1], pa1[rq]);
        pa1[rq] = fmaf(hv.z, wh1[4*q+2], pa1[rq]); pa1[rq] = fmaf(hv.w, wh1[4*q+3], pa1[rq]);
        pa0[rq] = fmaf(ev.x, wi0[4*q+0], pa0[rq]); pa0[rq] = fmaf(ev.y, wi0[4*q+1], pa0[rq]);
        pa0[rq] = fmaf(ev.z, wi0[4*q+2], pa0[rq]); pa0[rq] = fmaf(ev.w, wi0[4*q+3], pa0[rq]);
        pa1[rq] = fmaf(ev.x, wi1[4*q+0], pa1[rq]); pa1[rq] = fmaf(ev.y, wi1[4*q+1], pa1[rq]);
        pa1[rq] = fmaf(ev.z, wi1[4*q+2], pa1[rq]); pa1[rq] = fmaf(ev.w, wi1[4*q+3], pa1[rq]);
      }
    }
#pragma unroll
    for (int rq = 0; rq < 4; ++rq) {
      part[eg][rq][f0]   = pa0[rq];
      part[eg][rq][f0+1] = pa1[rq];
    }
    __syncthreads();
    float acc = bc;
#pragma unroll
    for (int g = 0; g < 8; ++g) acc += part[g][row][ff];
    float hn = tanhf(acc);
    if (s + 1 < SEQ) emb_lds[cur ^ 1][row][ff] = nxt;
    h_lds[row][ff] = hn;
    __syncthreads();
    cur ^= 1;
  }
  float hv = h_lds[row][ff];
  float sq = hv * hv;
#pragma unroll
  for (int off = 32; off > 0; off >>= 1) sq += __shfl_xor(sq, off, 64);
  if ((t & 63) == 0) red[t >> 6] = sq;
  __syncthreads();
  float nrm = sqrtf(red[row*2] + red[row*2 + 1]);
  out[(b0 + row)*EMB + ff] = hv / fmaxf(nrm, 1e-12f);
}

// ---------------------------------------------------------------------------
extern "C" void kernel_launch(void* const* d_in, const int* in_sizes, int n_in,
                              void* d_out, int out_size, void* d_ws, size_t ws_size,
                              hipStream_t stream) {
  const int*   x    = (const int*)  d_in[0];
  const float* emb  = (const float*)d_in[1];
  const float* Win  = (const float*)d_in[2];
  const float* bin  = (const float*)d_in[3];
  const float* Wh   = (const float*)d_in[4];
  const float* bh   = (const float*)d_in[5];
  float* out = (float*)d_out;

  const size_t need = (size_t)VOCAB * EMB * sizeof(unsigned short);  // 25.6 MB
  if (ws_size >= need) {
    unsigned short* embb = (unsigned short*)d_ws;
    cvt_emb<<<(VOCAB*EMB)/(256*8), 256, 0, stream>>>(emb, embb);
    rnn5<<<BATCH/4, 512, 0, stream>>>(x, embb, Win, bin, Wh, bh, out);
  } else {
    rnn_fused<<<BATCH/4, 512, 0, stream>>>(x, emb, Win, bin, Wh, bh, out);
  }
}